// Round 6
// baseline (463.866 us; speedup 1.0000x reference)
//
#include <hip/hip_runtime.h>

static constexpr int NN = 32768;   // nodes
static constexpr int NE = 262144;  // edges
static constexpr int NG = 1024;    // graphs

__device__ __forceinline__ float4 ld4(const float* p){ return *reinterpret_cast<const float4*>(p); }
__device__ __forceinline__ void st4(float* p, const float4 v){ *reinterpret_cast<float4*>(p) = v; }
__device__ __forceinline__ void fma4(float4& a, const float s, const float4 w){
  a.x = fmaf(s, w.x, a.x); a.y = fmaf(s, w.y, a.y); a.z = fmaf(s, w.z, a.z); a.w = fmaf(s, w.w, a.w);
}
__device__ __forceinline__ unsigned short f2bf(float f){
  unsigned x = __float_as_uint(f);
  return (unsigned short)((x + 0x7FFFu + ((x >> 16) & 1u)) >> 16);  // RNE
}
__device__ __forceinline__ float bf2f(unsigned short u){
  return __uint_as_float((unsigned)u << 16);
}

// ---------- fused setup: node_enc (blocks 0..8191) | hist (8192..9215) | precomp (9216..9272) ----------
__global__ __launch_bounds__(256) void k_setup(const float* __restrict__ nf, const float* __restrict__ Wn,
                                               const float* __restrict__ bn, float* __restrict__ h,
                                               const int* __restrict__ toi, int* __restrict__ deg,
                                               const float* __restrict__ Wm1, const float* __restrict__ bm1,
                                               const float* __restrict__ Wm2, const float* __restrict__ bm2,
                                               const float* __restrict__ Wu,
                                               const float* __restrict__ We, const float* __restrict__ be,
                                               float* __restrict__ Wupd, float* __restrict__ Wcomb,
                                               float* __restrict__ c0, float* __restrict__ Wec,
                                               float* __restrict__ ball) {
  int b = blockIdx.x;
  int tid = threadIdx.x;
  if (b < 8192) {
    __shared__ __align__(16) float Wn_s[32*64];
    for (int i = tid; i < 32*64; i += 256) Wn_s[i] = Wn[i];
    __syncthreads();
    int j = tid & 63, nl = tid >> 6;
    int n = b*4 + nl;
    const float* r = nf + n*32;
    float acc = bn[j];
    #pragma unroll
    for (int k = 0; k < 32; ++k) acc = fmaf(r[k], Wn_s[k*64+j], acc);
    h[n*64+j] = acc;
  } else if (b < 8192 + 1024) {
    int e = (b - 8192)*256 + tid;
    atomicAdd(&deg[toi[e]], 1);
  } else {
    int idx = (b - 9216)*256 + tid;
    if (idx < 4096) {
      int k = idx >> 6, j = idx & 63;
      Wupd[idx] = Wu[k*64 + j] + ((k == j) ? 1.f : 0.f);
    } else if (idx < 12288) {
      int i2 = idx - 4096;
      int k = i2 >> 6, j = i2 & 63;
      float s = 0.f;
      for (int i = 0; i < 128; ++i) s = fmaf(Wm2[k*128 + i], Wu[(64+i)*64 + j], s);
      Wcomb[i2] = s;
    } else if (idx < 12352) {
      int j = idx - 12288;
      float s = 0.f;
      for (int i = 0; i < 128; ++i) s = fmaf(bm2[i], Wu[(64+i)*64 + j], s);
      c0[j] = s;
    } else if (idx < 14400) {
      int i2 = idx - 12352;
      int k = i2 >> 7, j = i2 & 127;
      float s = 0.f;
      for (int i = 0; i < 16; ++i) s = fmaf(We[k*16 + i], Wm1[(128+i)*128 + j], s);
      Wec[i2] = s;
    } else if (idx < 14528) {
      int j = idx - 14400;
      float s = bm1[j];
      for (int i = 0; i < 16; ++i) s = fmaf(be[i], Wm1[(128+i)*128 + j], s);
      ball[j] = s;
    }
  }
}

// ---------- exclusive scan of deg[32768] -> rowptr[32769] ----------
__global__ __launch_bounds__(1024) void k_scan(const int* __restrict__ deg, int* __restrict__ rowptr) {
  __shared__ int sums[1024];
  int t = threadIdx.x;
  int base = t * 32;
  int local[32];
  int s = 0;
  #pragma unroll
  for (int i = 0; i < 32; ++i) { local[i] = s; s += deg[base + i]; }
  sums[t] = s;
  __syncthreads();
  for (int off = 1; off < 1024; off <<= 1) {
    int tmp = (t >= off) ? sums[t - off] : 0;
    __syncthreads();
    sums[t] += tmp;
    __syncthreads();
  }
  int boff = sums[t] - s;
  #pragma unroll
  for (int i = 0; i < 32; ++i) rowptr[base + i] = boff + local[i];
  if (t == 1023) rowptr[NN] = sums[1023];
}

// ---------- scatter edges into SoA CSR: fromArr[slot] = from[e]; eidxArr[slot] = e ----------
__global__ __launch_bounds__(256) void k_scatter(const int* __restrict__ from, const int* __restrict__ toi,
                                                 const int* __restrict__ rowptr, int* __restrict__ cursor,
                                                 int* __restrict__ fromArr, int* __restrict__ eidxArr) {
  int e = blockIdx.x*256 + threadIdx.x;
  int v = toi[e];
  int pos = atomicAdd(&cursor[v], 1);
  int slot = rowptr[v] + pos;
  fromArr[slot] = from[e];
  eidxArr[slot] = e;
}

// ---------- Tedge(NE x 128, bf16) = ef[eidx[s]] @ Wec   (step-invariant edge-MLP term, CSR order) ----------
__global__ __launch_bounds__(256) void k_tgemm(const float* __restrict__ ef,
                                               const int* __restrict__ eidxArr,
                                               const float* __restrict__ Wec,
                                               unsigned short* __restrict__ Tp) {
  __shared__ __align__(16) float Wec_s[16*128];
  __shared__ __align__(16) float efp_s[128*16];
  __shared__ int eidx_s[128];
  int tid = threadIdx.x;
  size_t e0 = (size_t)blockIdx.x * 128;
  for (int i = tid; i < 2048; i += 256) Wec_s[i] = Wec[i];
  if (tid < 128) eidx_s[tid] = eidxArr[e0 + tid];
  __syncthreads();
  for (int i = tid; i < 512; i += 256) {
    int el = i >> 2, k4 = (i & 3) << 2;
    st4(&efp_s[el*16 + k4], ld4(ef + (size_t)eidx_s[el]*16 + k4));
  }
  __syncthreads();
  int j4 = (tid & 31) * 4;
  int el0 = tid >> 5;   // 0..7
  for (int pass = 0; pass < 16; ++pass) {
    int el = el0 + pass*8;
    const float* er = &efp_s[el*16];
    float4 acc = make_float4(0,0,0,0);
    #pragma unroll
    for (int k = 0; k < 16; ++k) fma4(acc, er[k], ld4(&Wec_s[k*128 + j4]));
    ushort4 o;
    o.x = f2bf(acc.x); o.y = f2bf(acc.y); o.z = f2bf(acc.z); o.w = f2bf(acc.w);
    *reinterpret_cast<ushort4*>(Tp + (e0 + el)*128 + j4) = o;
  }
}

// ---------- Af = h @ Wm1[0:64] ; Atb = h @ Wm1[64:128] + ball  (persistent: W staged once) ----------
__global__ __launch_bounds__(256) void k_agemm(const float* __restrict__ h,
                                               const float* __restrict__ Wm1,
                                               const float* __restrict__ ball,
                                               float* __restrict__ Af,
                                               float* __restrict__ Atb) {
  __shared__ __align__(16) float W_s[64*256];
  __shared__ __align__(16) float h_s[32*64];
  int tid = threadIdx.x;
  for (int idx = tid; idx < 64*256; idx += 256) {
    int k = idx >> 8, j = idx & 255;
    W_s[idx] = (j < 128) ? Wm1[k*128 + j] : Wm1[(64+k)*128 + (j-128)];
  }
  int cg = tid & 63;   // cols 4cg..4cg+3 of 256
  int ng = tid >> 6;   // nodes ng, ng+4, ..., ng+28
  float4 b4 = make_float4(0,0,0,0);
  if (cg >= 32) b4 = ld4(ball + 4*cg - 128);
  for (int tile = blockIdx.x; tile < 1024; tile += gridDim.x) {
    int base = tile * 32;
    __syncthreads();
    for (int idx = tid; idx < 2048; idx += 256) h_s[idx] = h[base*64 + idx];
    __syncthreads();
    float4 acc[8];
    #pragma unroll
    for (int i = 0; i < 8; ++i) acc[i] = make_float4(0,0,0,0);
    for (int k4 = 0; k4 < 16; ++k4) {
      float4 w[4];
      #pragma unroll
      for (int q = 0; q < 4; ++q) w[q] = ld4(&W_s[(k4*4+q)*256 + 4*cg]);
      #pragma unroll
      for (int i = 0; i < 8; ++i) {
        float4 h4 = ld4(&h_s[(ng + 4*i)*64 + k4*4]);
        fma4(acc[i], h4.x, w[0]); fma4(acc[i], h4.y, w[1]);
        fma4(acc[i], h4.z, w[2]); fma4(acc[i], h4.w, w[3]);
      }
    }
    if (cg < 32) {
      #pragma unroll
      for (int i = 0; i < 8; ++i) {
        int n = base + ng + 4*i;
        st4(&Af[(size_t)n*128 + 4*cg], acc[i]);
      }
    } else {
      int col = 4*cg - 128;
      #pragma unroll
      for (int i = 0; i < 8; ++i) {
        int n = base + ng + 4*i;
        float4 r = acc[i];
        r.x += b4.x; r.y += b4.y; r.z += b4.z; r.w += b4.w;
        st4(&Atb[(size_t)n*128 + col], r);
      }
    }
  }
}

// ---------- u[v] = sum_{s in row v} relu(Af[from[s]] + Atb[v] + T[s]) ----------
__global__ __launch_bounds__(128) void k_aggregate(const float* __restrict__ Af,
                                                   const float* __restrict__ Atb,
                                                   const int* __restrict__ rowptr,
                                                   const int* __restrict__ fromArr,
                                                   const unsigned short* __restrict__ Tp,
                                                   float* __restrict__ u) {
  int j = threadIdx.x;  // 0..127
  int v0 = blockIdx.x * 8;
  for (int v = v0; v < v0 + 8; ++v) {
    float atv = Atb[(size_t)v*128 + j];
    int s0 = rowptr[v], s1 = rowptr[v+1];
    float acc = 0.f;
    int s = s0;
    for (; s + 8 <= s1; s += 8) {
      int f0 = fromArr[s],   f1 = fromArr[s+1], f2 = fromArr[s+2], f3 = fromArr[s+3];
      int f4 = fromArr[s+4], f5 = fromArr[s+5], f6 = fromArr[s+6], f7 = fromArr[s+7];
      float a0 = Af[(size_t)f0*128 + j];
      float a1 = Af[(size_t)f1*128 + j];
      float a2 = Af[(size_t)f2*128 + j];
      float a3 = Af[(size_t)f3*128 + j];
      float a4 = Af[(size_t)f4*128 + j];
      float a5 = Af[(size_t)f5*128 + j];
      float a6 = Af[(size_t)f6*128 + j];
      float a7 = Af[(size_t)f7*128 + j];
      unsigned short t0 = Tp[(size_t)(s  )*128 + j];
      unsigned short t1 = Tp[(size_t)(s+1)*128 + j];
      unsigned short t2 = Tp[(size_t)(s+2)*128 + j];
      unsigned short t3 = Tp[(size_t)(s+3)*128 + j];
      unsigned short t4 = Tp[(size_t)(s+4)*128 + j];
      unsigned short t5 = Tp[(size_t)(s+5)*128 + j];
      unsigned short t6 = Tp[(size_t)(s+6)*128 + j];
      unsigned short t7 = Tp[(size_t)(s+7)*128 + j];
      acc += fmaxf(a0 + atv + bf2f(t0), 0.f) + fmaxf(a1 + atv + bf2f(t1), 0.f)
           + fmaxf(a2 + atv + bf2f(t2), 0.f) + fmaxf(a3 + atv + bf2f(t3), 0.f)
           + fmaxf(a4 + atv + bf2f(t4), 0.f) + fmaxf(a5 + atv + bf2f(t5), 0.f)
           + fmaxf(a6 + atv + bf2f(t6), 0.f) + fmaxf(a7 + atv + bf2f(t7), 0.f);
    }
    for (; s + 4 <= s1; s += 4) {
      int f0 = fromArr[s], f1 = fromArr[s+1], f2 = fromArr[s+2], f3 = fromArr[s+3];
      float a0 = Af[(size_t)f0*128 + j];
      float a1 = Af[(size_t)f1*128 + j];
      float a2 = Af[(size_t)f2*128 + j];
      float a3 = Af[(size_t)f3*128 + j];
      unsigned short t0 = Tp[(size_t)(s  )*128 + j];
      unsigned short t1 = Tp[(size_t)(s+1)*128 + j];
      unsigned short t2 = Tp[(size_t)(s+2)*128 + j];
      unsigned short t3 = Tp[(size_t)(s+3)*128 + j];
      acc += fmaxf(a0 + atv + bf2f(t0), 0.f) + fmaxf(a1 + atv + bf2f(t1), 0.f)
           + fmaxf(a2 + atv + bf2f(t2), 0.f) + fmaxf(a3 + atv + bf2f(t3), 0.f);
    }
    for (; s < s1; ++s) {
      int f = fromArr[s];
      float a = Af[(size_t)f*128 + j];
      unsigned short t = Tp[(size_t)s*128 + j];
      acc += fmaxf(a + atv + bf2f(t), 0.f);
    }
    u[(size_t)v*128 + j] = acc;
  }
}

// ---------- h_out = h@Wupd + u@Wcomb + deg*c0 + bu  (persistent) ----------
__global__ __launch_bounds__(256) void k_update(const float* __restrict__ h, const float* __restrict__ u,
                                                const int* __restrict__ deg,
                                                const float* __restrict__ Wupd, const float* __restrict__ Wcomb,
                                                const float* __restrict__ c0, const float* __restrict__ bu,
                                                float* __restrict__ hout) {
  __shared__ __align__(16) float Wall_s[192*64];
  __shared__ __align__(16) float h_s[32*64];
  __shared__ __align__(16) float u_s[32*128];
  int tid = threadIdx.x;
  for (int idx = tid; idx < 4096; idx += 256) Wall_s[idx] = Wupd[idx];
  for (int idx = tid; idx < 8192; idx += 256) Wall_s[4096 + idx] = Wcomb[idx];
  int cg = tid & 15;
  int nl = tid >> 4;
  float4 c04 = ld4(c0 + 4*cg);
  float4 bu4 = ld4(bu + 4*cg);
  for (int tile = blockIdx.x; tile < 1024; tile += gridDim.x) {
    int base = tile * 32;
    __syncthreads();
    for (int idx = tid; idx < 2048; idx += 256) h_s[idx] = h[base*64 + idx];
    for (int idx = tid; idx < 4096; idx += 256) u_s[idx] = u[base*128 + idx];
    __syncthreads();
    float4 acc[2];
    acc[0] = make_float4(0,0,0,0); acc[1] = make_float4(0,0,0,0);
    for (int k4 = 0; k4 < 16; ++k4) {
      float4 w[4];
      #pragma unroll
      for (int q = 0; q < 4; ++q) w[q] = ld4(&Wall_s[(k4*4+q)*64 + 4*cg]);
      #pragma unroll
      for (int i = 0; i < 2; ++i) {
        float4 h4 = ld4(&h_s[(nl + 16*i)*64 + k4*4]);
        fma4(acc[i], h4.x, w[0]); fma4(acc[i], h4.y, w[1]);
        fma4(acc[i], h4.z, w[2]); fma4(acc[i], h4.w, w[3]);
      }
    }
    for (int k4 = 0; k4 < 32; ++k4) {
      float4 w[4];
      #pragma unroll
      for (int q = 0; q < 4; ++q) w[q] = ld4(&Wall_s[(64 + k4*4+q)*64 + 4*cg]);
      #pragma unroll
      for (int i = 0; i < 2; ++i) {
        float4 u4 = ld4(&u_s[(nl + 16*i)*128 + k4*4]);
        fma4(acc[i], u4.x, w[0]); fma4(acc[i], u4.y, w[1]);
        fma4(acc[i], u4.z, w[2]); fma4(acc[i], u4.w, w[3]);
      }
    }
    #pragma unroll
    for (int i = 0; i < 2; ++i) {
      int n = base + nl + 16*i;
      float dg = (float)deg[n];
      float4 r = acc[i];
      r.x += dg*c04.x + bu4.x; r.y += dg*c04.y + bu4.y;
      r.z += dg*c04.z + bu4.z; r.w += dg*c04.w + bu4.w;
      st4(&hout[(size_t)n*64 + 4*cg], r);
    }
  }
}

// ---------- per-graph gate+pool (persistent): gv[g] = sum_n sigmoid(.)*(.) ----------
__global__ __launch_bounds__(256) void k_gate(const float* __restrict__ h,
                                              const float* __restrict__ Wa, const float* __restrict__ ba,
                                              float* __restrict__ gv) {
  __shared__ __align__(16) float Wa_s[64*256];
  __shared__ __align__(16) float h_s[32*64];
  __shared__ __align__(16) float4 part_s[8][32];
  int tid = threadIdx.x;
  for (int idx = tid; idx < 64*256; idx += 256) Wa_s[idx] = Wa[idx];
  int cg = tid & 31;
  int nl = tid >> 5;
  float4 ba4a = ld4(ba + 4*cg);
  float4 ba4b = ld4(ba + 128 + 4*cg);
  for (int g = blockIdx.x; g < NG; g += gridDim.x) {
    __syncthreads();
    for (int idx = tid; idx < 2048; idx += 256) h_s[idx] = h[(size_t)g*2048 + idx];
    __syncthreads();
    float4 aA[4], aB[4];
    #pragma unroll
    for (int i = 0; i < 4; ++i) { aA[i] = make_float4(0,0,0,0); aB[i] = make_float4(0,0,0,0); }
    for (int k4 = 0; k4 < 16; ++k4) {
      float4 wa[4], wb[4];
      #pragma unroll
      for (int q = 0; q < 4; ++q) {
        wa[q] = ld4(&Wa_s[(k4*4+q)*256 + 4*cg]);
        wb[q] = ld4(&Wa_s[(k4*4+q)*256 + 128 + 4*cg]);
      }
      #pragma unroll
      for (int i = 0; i < 4; ++i) {
        float4 h4 = ld4(&h_s[(nl + 8*i)*64 + k4*4]);
        fma4(aA[i], h4.x, wa[0]); fma4(aA[i], h4.y, wa[1]); fma4(aA[i], h4.z, wa[2]); fma4(aA[i], h4.w, wa[3]);
        fma4(aB[i], h4.x, wb[0]); fma4(aB[i], h4.y, wb[1]); fma4(aB[i], h4.z, wb[2]); fma4(aB[i], h4.w, wb[3]);
      }
    }
    float4 sum = make_float4(0,0,0,0);
    #pragma unroll
    for (int i = 0; i < 4; ++i) {
      float ax = aA[i].x + ba4a.x, ay = aA[i].y + ba4a.y, az = aA[i].z + ba4a.z, aw = aA[i].w + ba4a.w;
      float bx = aB[i].x + ba4b.x, by = aB[i].y + ba4b.y, bz = aB[i].z + ba4b.z, bw = aB[i].w + ba4b.w;
      sum.x += bx / (1.f + __expf(-ax));
      sum.y += by / (1.f + __expf(-ay));
      sum.z += bz / (1.f + __expf(-az));
      sum.w += bw / (1.f + __expf(-aw));
    }
    part_s[nl][cg] = sum;
    __syncthreads();
    if (tid < 32) {
      float4 s = part_s[0][tid];
      #pragma unroll
      for (int n = 1; n < 8; ++n) {
        float4 p = part_s[n][tid];
        s.x += p.x; s.y += p.y; s.z += p.z; s.w += p.w;
      }
      st4(&gv[(size_t)g*128 + tid*4], s);
    }
  }
}

// ---------- pairs: out[p] = -sum relu((gv[2p]-gv[2p+1]) @ Wg)  (bg cancels) ----------
__global__ __launch_bounds__(64) void k_hinge(const float* __restrict__ gv,
                                              const float* __restrict__ Wg,
                                              float* __restrict__ out) {
  __shared__ float d_s[128];
  int p = blockIdx.x, tid = threadIdx.x;
  d_s[tid]      = gv[(2*p)*128 + tid]      - gv[(2*p+1)*128 + tid];
  d_s[tid + 64] = gv[(2*p)*128 + 64 + tid] - gv[(2*p+1)*128 + 64 + tid];
  __syncthreads();
  float a0 = 0.f, a1 = 0.f;
  for (int k = 0; k < 128; ++k) {
    float d = d_s[k];
    a0 = fmaf(d, Wg[k*128 + tid], a0);
    a1 = fmaf(d, Wg[k*128 + 64 + tid], a1);
  }
  float r = fmaxf(a0, 0.f) + fmaxf(a1, 0.f);
  #pragma unroll
  for (int off = 32; off > 0; off >>= 1) r += __shfl_down(r, off, 64);
  if (tid == 0) out[p] = -r;
}

extern "C" void kernel_launch(void* const* d_in, const int* in_sizes, int n_in,
                              void* d_out, int out_size, void* d_ws, size_t ws_size,
                              hipStream_t stream) {
  const float* nf  = (const float*)d_in[0];
  const float* ef  = (const float*)d_in[1];
  const int*   from= (const int*)d_in[2];
  const int*   toi = (const int*)d_in[3];
  const float* Wn  = (const float*)d_in[5];
  const float* bn  = (const float*)d_in[6];
  const float* We  = (const float*)d_in[7];
  const float* be  = (const float*)d_in[8];
  const float* Wm1 = (const float*)d_in[9];
  const float* bm1 = (const float*)d_in[10];
  const float* Wm2 = (const float*)d_in[11];
  const float* bm2 = (const float*)d_in[12];
  const float* Wu  = (const float*)d_in[13];
  const float* bu  = (const float*)d_in[14];
  const float* Wa  = (const float*)d_in[15];
  const float* ba  = (const float*)d_in[16];
  const float* Wg  = (const float*)d_in[17];
  float* out = (float*)d_out;

  float* fb    = (float*)d_ws;
  float* h0    = fb;                    // 2,097,152 floats
  float* h1    = h0 + 2097152;          // 2,097,152
  float* Af    = h1 + 2097152;          // 4,194,304
  float* Atb   = Af + 4194304;          // 4,194,304
  float* u     = Atb + 4194304;         // 4,194,304
  float* gv    = u + 4194304;           // 131,072
  float* Wupd  = gv + 131072;           // 4,096
  float* Wcomb = Wupd + 4096;           // 8,192
  float* c0    = Wcomb + 8192;          // 64
  float* Wec   = c0 + 64;               // 2,048
  float* ball  = Wec + 2048;            // 128
  unsigned short* Tp = (unsigned short*)(ball + 128);  // NE*128 bf16
  int*   fromArr = (int*)(Tp + (size_t)NE*128);        // NE
  int*   eidxArr = fromArr + NE;        // NE
  int*   deg   = eidxArr + NE;          // NN
  int*   rowptr= deg + NN;              // NN+1
  int*   cursor= rowptr + NN + 1;       // NN

  hipMemsetAsync(deg, 0, (size_t)(NN + (NN+1) + NN) * sizeof(int), stream);

  k_setup<<<9273, 256, 0, stream>>>(nf, Wn, bn, h0, toi, deg,
                                    Wm1, bm1, Wm2, bm2, Wu, We, be,
                                    Wupd, Wcomb, c0, Wec, ball);
  k_scan<<<1, 1024, 0, stream>>>(deg, rowptr);
  k_scatter<<<NE/256, 256, 0, stream>>>(from, toi, rowptr, cursor, fromArr, eidxArr);
  k_tgemm<<<NE/128, 256, 0, stream>>>(ef, eidxArr, Wec, Tp);

  const float* hc = h0;
  float* hn = h1;
  for (int s = 0; s < 3; ++s) {
    k_agemm<<<512, 256, 0, stream>>>(hc, Wm1, ball, Af, Atb);
    k_aggregate<<<NN/8, 128, 0, stream>>>(Af, Atb, rowptr, fromArr, Tp, u);
    k_update<<<512, 256, 0, stream>>>(hc, u, deg, Wupd, Wcomb, c0, bu, hn);
    float* t = (float*)hc; hc = hn; hn = t;
  }
  k_gate<<<512, 256, 0, stream>>>(hc, Wa, ba, gv);
  k_hinge<<<512, 64, 0, stream>>>(gv, Wg, out);
}

// Round 9
// 418.556 us; speedup vs baseline: 1.1083x; 1.1083x over previous
//
#include <hip/hip_runtime.h>

static constexpr int NN = 32768;   // nodes
static constexpr int NE = 262144;  // edges
static constexpr int NG = 1024;    // graphs

typedef __attribute__((ext_vector_type(8))) short short8v;
typedef __attribute__((ext_vector_type(4))) float f32x4;
union Frag { short8v v; short4 p[2]; };

__device__ __forceinline__ float4 ld4(const float* p){ return *reinterpret_cast<const float4*>(p); }
__device__ __forceinline__ void st4(float* p, const float4 v){ *reinterpret_cast<float4*>(p) = v; }
__device__ __forceinline__ void fma4(float4& a, const float s, const float4 w){
  a.x = fmaf(s, w.x, a.x); a.y = fmaf(s, w.y, a.y); a.z = fmaf(s, w.z, a.z); a.w = fmaf(s, w.w, a.w);
}
__device__ __forceinline__ unsigned short f2bf(float f){
  unsigned x = __float_as_uint(f);
  return (unsigned short)((x + 0x7FFFu + ((x >> 16) & 1u)) >> 16);  // RNE
}
__device__ __forceinline__ float bf2f(unsigned short u){
  return __uint_as_float((unsigned)u << 16);
}

// ---------- fused setup: node_enc (blocks 0..8191) | hist (8192..9215) | precomp (9216..9336) ----------
// precomp extras: W2f = Wm1 repacked to bf16 MFMA B-fragment order:
//   t = (((ks*16+ct)*64 + lane)*8 + i); k = ks*32 + (i>>2)*16 + (lane>>4)*4 + (i&3); col = ct*16 + (lane&15)
__global__ __launch_bounds__(256) void k_setup(const float* __restrict__ nf, const float* __restrict__ Wn,
                                               const float* __restrict__ bn, float* __restrict__ h,
                                               unsigned short* __restrict__ hb,
                                               const int* __restrict__ toi, int* __restrict__ deg,
                                               const float* __restrict__ Wm1, const float* __restrict__ bm1,
                                               const float* __restrict__ Wm2, const float* __restrict__ bm2,
                                               const float* __restrict__ Wu,
                                               const float* __restrict__ We, const float* __restrict__ be,
                                               float* __restrict__ Wupd, float* __restrict__ Wcomb,
                                               float* __restrict__ c0, float* __restrict__ Wec,
                                               float* __restrict__ ball, unsigned short* __restrict__ W2f) {
  int b = blockIdx.x;
  int tid = threadIdx.x;
  if (b < 8192) {
    __shared__ __align__(16) float Wn_s[32*64];
    for (int i = tid; i < 32*64; i += 256) Wn_s[i] = Wn[i];
    __syncthreads();
    int j = tid & 63, nl = tid >> 6;
    int n = b*4 + nl;
    const float* r = nf + n*32;
    float acc = bn[j];
    #pragma unroll
    for (int k = 0; k < 32; ++k) acc = fmaf(r[k], Wn_s[k*64+j], acc);
    h[n*64+j] = acc;
    hb[n*64+j] = f2bf(acc);
  } else if (b < 8192 + 1024) {
    int e = (b - 8192)*256 + tid;
    atomicAdd(&deg[toi[e]], 1);
  } else {
    int idx = (b - 9216)*256 + tid;
    if (idx < 4096) {
      int k = idx >> 6, j = idx & 63;
      Wupd[idx] = Wu[k*64 + j] + ((k == j) ? 1.f : 0.f);
    } else if (idx < 12288) {
      int i2 = idx - 4096;
      int k = i2 >> 6, j = i2 & 63;
      float s = 0.f;
      for (int i = 0; i < 128; ++i) s = fmaf(Wm2[k*128 + i], Wu[(64+i)*64 + j], s);
      Wcomb[i2] = s;
    } else if (idx < 12352) {
      int j = idx - 12288;
      float s = 0.f;
      for (int i = 0; i < 128; ++i) s = fmaf(bm2[i], Wu[(64+i)*64 + j], s);
      c0[j] = s;
    } else if (idx < 14400) {
      int i2 = idx - 12352;
      int k = i2 >> 7, j = i2 & 127;
      float s = 0.f;
      for (int i = 0; i < 16; ++i) s = fmaf(We[k*16 + i], Wm1[(128+i)*128 + j], s);
      Wec[i2] = s;
    } else if (idx < 14528) {
      int j = idx - 14400;
      float s = bm1[j];
      for (int i = 0; i < 16; ++i) s = fmaf(be[i], Wm1[(128+i)*128 + j], s);
      ball[j] = s;
    } else if (idx < 14528 + 16384) {
      int t = idx - 14528;
      int ks = t >> 13;
      int r = t & 8191;
      int ct = r >> 9;
      int r2 = r & 511;
      int lane = r2 >> 3;
      int i = r2 & 7;
      int k = ks*32 + ((i>>2)<<4) + ((lane>>4)<<2) + (i&3);
      int col = ct*16 + (lane & 15);
      float val = (col < 128) ? Wm1[k*128 + col] : Wm1[(64+k)*128 + (col-128)];
      W2f[t] = f2bf(val);
    }
  }
}

// ---------- exclusive scan of deg[32768] -> rowptr[32769] ----------
__global__ __launch_bounds__(1024) void k_scan(const int* __restrict__ deg, int* __restrict__ rowptr) {
  __shared__ int sums[1024];
  int t = threadIdx.x;
  int base = t * 32;
  int local[32];
  int s = 0;
  #pragma unroll
  for (int i = 0; i < 32; ++i) { local[i] = s; s += deg[base + i]; }
  sums[t] = s;
  __syncthreads();
  for (int off = 1; off < 1024; off <<= 1) {
    int tmp = (t >= off) ? sums[t - off] : 0;
    __syncthreads();
    sums[t] += tmp;
    __syncthreads();
  }
  int boff = sums[t] - s;
  #pragma unroll
  for (int i = 0; i < 32; ++i) rowptr[base + i] = boff + local[i];
  if (t == 1023) rowptr[NN] = sums[1023];
}

// ---------- scatter edges into SoA CSR ----------
__global__ __launch_bounds__(256) void k_scatter(const int* __restrict__ from, const int* __restrict__ toi,
                                                 const int* __restrict__ rowptr, int* __restrict__ cursor,
                                                 int* __restrict__ fromArr, int* __restrict__ eidxArr) {
  int e = blockIdx.x*256 + threadIdx.x;
  int v = toi[e];
  int pos = atomicAdd(&cursor[v], 1);
  int slot = rowptr[v] + pos;
  fromArr[slot] = from[e];
  eidxArr[slot] = e;
}

// ---------- Tedge(NE x 128, bf16) = ef[eidx[s]] @ Wec  (step-invariant, CSR order) ----------
__global__ __launch_bounds__(256) void k_tgemm(const float* __restrict__ ef,
                                               const int* __restrict__ eidxArr,
                                               const float* __restrict__ Wec,
                                               unsigned short* __restrict__ Tp) {
  __shared__ __align__(16) float Wec_s[16*128];
  __shared__ __align__(16) float efp_s[128*16];
  __shared__ int eidx_s[128];
  int tid = threadIdx.x;
  size_t e0 = (size_t)blockIdx.x * 128;
  for (int i = tid; i < 2048; i += 256) Wec_s[i] = Wec[i];
  if (tid < 128) eidx_s[tid] = eidxArr[e0 + tid];
  __syncthreads();
  for (int i = tid; i < 512; i += 256) {
    int el = i >> 2, k4 = (i & 3) << 2;
    st4(&efp_s[el*16 + k4], ld4(ef + (size_t)eidx_s[el]*16 + k4));
  }
  __syncthreads();
  int j4 = (tid & 31) * 4;
  int el0 = tid >> 5;
  for (int pass = 0; pass < 16; ++pass) {
    int el = el0 + pass*8;
    const float* er = &efp_s[el*16];
    float4 acc = make_float4(0,0,0,0);
    #pragma unroll
    for (int k = 0; k < 16; ++k) fma4(acc, er[k], ld4(&Wec_s[k*128 + j4]));
    ushort4 o;
    o.x = f2bf(acc.x); o.y = f2bf(acc.y); o.z = f2bf(acc.z); o.w = f2bf(acc.w);
    *reinterpret_cast<ushort4*>(Tp + (e0 + el)*128 + j4) = o;
  }
}

// ---------- MFMA agemm: Afb/Atbb (bf16) = hb @ W2f (+ball)  ----------
__global__ __launch_bounds__(256) void k_agemm(const unsigned short* __restrict__ hb,
                                               const unsigned short* __restrict__ W2f,
                                               const float* __restrict__ ball,
                                               unsigned short* __restrict__ Afb,
                                               unsigned short* __restrict__ Atbb) {
  int tid = threadIdx.x;
  int wv = tid >> 6, lane = tid & 63;
  int n0 = blockIdx.x*64 + wv*16;
  int r = lane & 15, kg = lane >> 4;
  const unsigned short* hrow = hb + (size_t)(n0 + r)*64;
  Frag a0, a1;
  a0.p[0] = *reinterpret_cast<const short4*>(hrow + kg*4);
  a0.p[1] = *reinterpret_cast<const short4*>(hrow + 16 + kg*4);
  a1.p[0] = *reinterpret_cast<const short4*>(hrow + 32 + kg*4);
  a1.p[1] = *reinterpret_cast<const short4*>(hrow + 48 + kg*4);
  #pragma unroll
  for (int ct = 0; ct < 16; ++ct) {
    Frag b0, b1;
    b0.v = *reinterpret_cast<const short8v*>(W2f + ((size_t)(ct*64 + lane) << 3));
    b1.v = *reinterpret_cast<const short8v*>(W2f + ((size_t)((16+ct)*64 + lane) << 3));
    f32x4 acc = {0.f, 0.f, 0.f, 0.f};
    acc = __builtin_amdgcn_mfma_f32_16x16x32_bf16(a0.v, b0.v, acc, 0, 0, 0);
    acc = __builtin_amdgcn_mfma_f32_16x16x32_bf16(a1.v, b1.v, acc, 0, 0, 0);
    int cj = ct*16 + r;
    int nb = n0 + kg*4;
    if (cj < 128) {
      #pragma unroll
      for (int i = 0; i < 4; ++i)
        Afb[(size_t)(nb+i)*128 + cj] = f2bf(acc[i]);
    } else {
      float bb = ball[cj-128];
      #pragma unroll
      for (int i = 0; i < 4; ++i)
        Atbb[(size_t)(nb+i)*128 + (cj-128)] = f2bf(acc[i] + bb);
    }
  }
}

// ---------- u[v] = sum_{s in row v} relu(Afb[from[s]] + Atbb[v] + Tp[s]) ----------
__global__ __launch_bounds__(128) void k_aggregate(const unsigned short* __restrict__ Afb,
                                                   const unsigned short* __restrict__ Atbb,
                                                   const int* __restrict__ rowptr,
                                                   const int* __restrict__ fromArr,
                                                   const unsigned short* __restrict__ Tp,
                                                   float* __restrict__ u) {
  int j = threadIdx.x;  // 0..127
  int v0 = blockIdx.x * 8;
  for (int v = v0; v < v0 + 8; ++v) {
    float atv = bf2f(Atbb[(size_t)v*128 + j]);
    int s0 = rowptr[v], s1 = rowptr[v+1];
    float acc = 0.f;
    int s = s0;
    for (; s + 8 <= s1; s += 8) {
      int f0 = fromArr[s],   f1 = fromArr[s+1], f2 = fromArr[s+2], f3 = fromArr[s+3];
      int f4 = fromArr[s+4], f5 = fromArr[s+5], f6 = fromArr[s+6], f7 = fromArr[s+7];
      float a0 = bf2f(Afb[(size_t)f0*128 + j]);
      float a1 = bf2f(Afb[(size_t)f1*128 + j]);
      float a2 = bf2f(Afb[(size_t)f2*128 + j]);
      float a3 = bf2f(Afb[(size_t)f3*128 + j]);
      float a4 = bf2f(Afb[(size_t)f4*128 + j]);
      float a5 = bf2f(Afb[(size_t)f5*128 + j]);
      float a6 = bf2f(Afb[(size_t)f6*128 + j]);
      float a7 = bf2f(Afb[(size_t)f7*128 + j]);
      float t0 = bf2f(Tp[(size_t)(s  )*128 + j]);
      float t1 = bf2f(Tp[(size_t)(s+1)*128 + j]);
      float t2 = bf2f(Tp[(size_t)(s+2)*128 + j]);
      float t3 = bf2f(Tp[(size_t)(s+3)*128 + j]);
      float t4 = bf2f(Tp[(size_t)(s+4)*128 + j]);
      float t5 = bf2f(Tp[(size_t)(s+5)*128 + j]);
      float t6 = bf2f(Tp[(size_t)(s+6)*128 + j]);
      float t7 = bf2f(Tp[(size_t)(s+7)*128 + j]);
      acc += fmaxf(a0 + atv + t0, 0.f) + fmaxf(a1 + atv + t1, 0.f)
           + fmaxf(a2 + atv + t2, 0.f) + fmaxf(a3 + atv + t3, 0.f)
           + fmaxf(a4 + atv + t4, 0.f) + fmaxf(a5 + atv + t5, 0.f)
           + fmaxf(a6 + atv + t6, 0.f) + fmaxf(a7 + atv + t7, 0.f);
    }
    for (; s < s1; ++s) {
      int f = fromArr[s];
      float a = bf2f(Afb[(size_t)f*128 + j]);
      float t = bf2f(Tp[(size_t)s*128 + j]);
      acc += fmaxf(a + atv + t, 0.f);
    }
    u[(size_t)v*128 + j] = acc;
  }
}

// ---------- h_out = h@Wupd + u@Wcomb + deg*c0 + bu  (fp32, persistent; also emits bf16 h) ----------
__global__ __launch_bounds__(256) void k_update(const float* __restrict__ h, const float* __restrict__ u,
                                                const int* __restrict__ deg,
                                                const float* __restrict__ Wupd, const float* __restrict__ Wcomb,
                                                const float* __restrict__ c0, const float* __restrict__ bu,
                                                float* __restrict__ hout, unsigned short* __restrict__ hbout) {
  __shared__ __align__(16) float Wall_s[192*64];
  __shared__ __align__(16) float h_s[32*64];
  __shared__ __align__(16) float u_s[32*128];
  int tid = threadIdx.x;
  for (int idx = tid; idx < 4096; idx += 256) Wall_s[idx] = Wupd[idx];
  for (int idx = tid; idx < 8192; idx += 256) Wall_s[4096 + idx] = Wcomb[idx];
  int cg = tid & 15;
  int nl = tid >> 4;
  float4 c04 = ld4(c0 + 4*cg);
  float4 bu4 = ld4(bu + 4*cg);
  for (int tile = blockIdx.x; tile < 1024; tile += gridDim.x) {
    int base = tile * 32;
    __syncthreads();
    for (int idx = tid; idx < 2048; idx += 256) h_s[idx] = h[base*64 + idx];
    for (int idx = tid; idx < 4096; idx += 256) u_s[idx] = u[base*128 + idx];
    __syncthreads();
    float4 acc[2];
    acc[0] = make_float4(0,0,0,0); acc[1] = make_float4(0,0,0,0);
    for (int k4 = 0; k4 < 16; ++k4) {
      float4 w[4];
      #pragma unroll
      for (int q = 0; q < 4; ++q) w[q] = ld4(&Wall_s[(k4*4+q)*64 + 4*cg]);
      #pragma unroll
      for (int i = 0; i < 2; ++i) {
        float4 h4 = ld4(&h_s[(nl + 16*i)*64 + k4*4]);
        fma4(acc[i], h4.x, w[0]); fma4(acc[i], h4.y, w[1]);
        fma4(acc[i], h4.z, w[2]); fma4(acc[i], h4.w, w[3]);
      }
    }
    for (int k4 = 0; k4 < 32; ++k4) {
      float4 w[4];
      #pragma unroll
      for (int q = 0; q < 4; ++q) w[q] = ld4(&Wall_s[(64 + k4*4+q)*64 + 4*cg]);
      #pragma unroll
      for (int i = 0; i < 2; ++i) {
        float4 u4 = ld4(&u_s[(nl + 16*i)*128 + k4*4]);
        fma4(acc[i], u4.x, w[0]); fma4(acc[i], u4.y, w[1]);
        fma4(acc[i], u4.z, w[2]); fma4(acc[i], u4.w, w[3]);
      }
    }
    #pragma unroll
    for (int i = 0; i < 2; ++i) {
      int n = base + nl + 16*i;
      float dg = (float)deg[n];
      float4 r = acc[i];
      r.x += dg*c04.x + bu4.x; r.y += dg*c04.y + bu4.y;
      r.z += dg*c04.z + bu4.z; r.w += dg*c04.w + bu4.w;
      st4(&hout[(size_t)n*64 + 4*cg], r);
      ushort4 rb;
      rb.x = f2bf(r.x); rb.y = f2bf(r.y); rb.z = f2bf(r.z); rb.w = f2bf(r.w);
      *reinterpret_cast<ushort4*>(hbout + (size_t)n*64 + 4*cg) = rb;
    }
  }
}

// ---------- per-graph gate+pool (persistent) ----------
__global__ __launch_bounds__(256) void k_gate(const float* __restrict__ h,
                                              const float* __restrict__ Wa, const float* __restrict__ ba,
                                              float* __restrict__ gv) {
  __shared__ __align__(16) float Wa_s[64*256];
  __shared__ __align__(16) float h_s[32*64];
  __shared__ __align__(16) float4 part_s[8][32];
  int tid = threadIdx.x;
  for (int idx = tid; idx < 64*256; idx += 256) Wa_s[idx] = Wa[idx];
  int cg = tid & 31;
  int nl = tid >> 5;
  float4 ba4a = ld4(ba + 4*cg);
  float4 ba4b = ld4(ba + 128 + 4*cg);
  for (int g = blockIdx.x; g < NG; g += gridDim.x) {
    __syncthreads();
    for (int idx = tid; idx < 2048; idx += 256) h_s[idx] = h[(size_t)g*2048 + idx];
    __syncthreads();
    float4 aA[4], aB[4];
    #pragma unroll
    for (int i = 0; i < 4; ++i) { aA[i] = make_float4(0,0,0,0); aB[i] = make_float4(0,0,0,0); }
    for (int k4 = 0; k4 < 16; ++k4) {
      float4 wa[4], wb[4];
      #pragma unroll
      for (int q = 0; q < 4; ++q) {
        wa[q] = ld4(&Wa_s[(k4*4+q)*256 + 4*cg]);
        wb[q] = ld4(&Wa_s[(k4*4+q)*256 + 128 + 4*cg]);
      }
      #pragma unroll
      for (int i = 0; i < 4; ++i) {
        float4 h4 = ld4(&h_s[(nl + 8*i)*64 + k4*4]);
        fma4(aA[i], h4.x, wa[0]); fma4(aA[i], h4.y, wa[1]); fma4(aA[i], h4.z, wa[2]); fma4(aA[i], h4.w, wa[3]);
        fma4(aB[i], h4.x, wb[0]); fma4(aB[i], h4.y, wb[1]); fma4(aB[i], h4.z, wb[2]); fma4(aB[i], h4.w, wb[3]);
      }
    }
    float4 sum = make_float4(0,0,0,0);
    #pragma unroll
    for (int i = 0; i < 4; ++i) {
      float ax = aA[i].x + ba4a.x, ay = aA[i].y + ba4a.y, az = aA[i].z + ba4a.z, aw = aA[i].w + ba4a.w;
      float bx = aB[i].x + ba4b.x, by = aB[i].y + ba4b.y, bz = aB[i].z + ba4b.z, bw = aB[i].w + ba4b.w;
      sum.x += bx / (1.f + __expf(-ax));
      sum.y += by / (1.f + __expf(-ay));
      sum.z += bz / (1.f + __expf(-az));
      sum.w += bw / (1.f + __expf(-aw));
    }
    part_s[nl][cg] = sum;
    __syncthreads();
    if (tid < 32) {
      float4 s = part_s[0][tid];
      #pragma unroll
      for (int n = 1; n < 8; ++n) {
        float4 p = part_s[n][tid];
        s.x += p.x; s.y += p.y; s.z += p.z; s.w += p.w;
      }
      st4(&gv[(size_t)g*128 + tid*4], s);
    }
  }
}

// ---------- pairs: out[p] = -sum relu((gv[2p]-gv[2p+1]) @ Wg) ----------
__global__ __launch_bounds__(64) void k_hinge(const float* __restrict__ gv,
                                              const float* __restrict__ Wg,
                                              float* __restrict__ out) {
  __shared__ float d_s[128];
  int p = blockIdx.x, tid = threadIdx.x;
  d_s[tid]      = gv[(2*p)*128 + tid]      - gv[(2*p+1)*128 + tid];
  d_s[tid + 64] = gv[(2*p)*128 + 64 + tid] - gv[(2*p+1)*128 + 64 + tid];
  __syncthreads();
  float a0 = 0.f, a1 = 0.f;
  for (int k = 0; k < 128; ++k) {
    float d = d_s[k];
    a0 = fmaf(d, Wg[k*128 + tid], a0);
    a1 = fmaf(d, Wg[k*128 + 64 + tid], a1);
  }
  float r = fmaxf(a0, 0.f) + fmaxf(a1, 0.f);
  #pragma unroll
  for (int off = 32; off > 0; off >>= 1) r += __shfl_down(r, off, 64);
  if (tid == 0) out[p] = -r;
}

extern "C" void kernel_launch(void* const* d_in, const int* in_sizes, int n_in,
                              void* d_out, int out_size, void* d_ws, size_t ws_size,
                              hipStream_t stream) {
  const float* nf  = (const float*)d_in[0];
  const float* ef  = (const float*)d_in[1];
  const int*   from= (const int*)d_in[2];
  const int*   toi = (const int*)d_in[3];
  const float* Wn  = (const float*)d_in[5];
  const float* bn  = (const float*)d_in[6];
  const float* We  = (const float*)d_in[7];
  const float* be  = (const float*)d_in[8];
  const float* Wm1 = (const float*)d_in[9];
  const float* bm1 = (const float*)d_in[10];
  const float* Wm2 = (const float*)d_in[11];
  const float* bm2 = (const float*)d_in[12];
  const float* Wu  = (const float*)d_in[13];
  const float* bu  = (const float*)d_in[14];
  const float* Wa  = (const float*)d_in[15];
  const float* ba  = (const float*)d_in[16];
  const float* Wg  = (const float*)d_in[17];
  float* out = (float*)d_out;

  float* fb    = (float*)d_ws;
  float* h0    = fb;                    // 2,097,152 floats
  float* h1    = h0 + 2097152;          // 2,097,152
  float* u     = h1 + 2097152;          // 4,194,304
  float* gv    = u + 4194304;           // 131,072
  float* Wupd  = gv + 131072;           // 4,096
  float* Wcomb = Wupd + 4096;           // 8,192
  float* c0    = Wcomb + 8192;          // 64
  float* Wec   = c0 + 64;               // 2,048
  float* ball  = Wec + 2048;            // 128
  unsigned short* hb0  = (unsigned short*)(ball + 128);   // NN*64
  unsigned short* hb1  = hb0 + (size_t)NN*64;             // NN*64
  unsigned short* Afb  = hb1 + (size_t)NN*64;             // NN*128
  unsigned short* Atbb = Afb + (size_t)NN*128;            // NN*128
  unsigned short* W2f  = Atbb + (size_t)NN*128;           // 16384
  unsigned short* Tp   = W2f + 16384;                     // NE*128
  int*   fromArr = (int*)(Tp + (size_t)NE*128);           // NE
  int*   eidxArr = fromArr + NE;        // NE
  int*   deg   = eidxArr + NE;          // NN
  int*   rowptr= deg + NN;              // NN+1
  int*   cursor= rowptr + NN + 1;       // NN

  // Zero-init the ENTIRE used workspace region every call: the harness
  // re-poisons d_ws to 0xAA before each timed launch, while the first
  // correctness call sees fresh (zero) pages. Forcing identical initial
  // state removes any poison-sensitivity (round-8 post-timing divergence).
  size_t used_bytes = (size_t)((char*)(cursor + NN) - (char*)d_ws);
  hipMemsetAsync(d_ws, 0, used_bytes, stream);

  k_setup<<<9337, 256, 0, stream>>>(nf, Wn, bn, h0, hb0, toi, deg,
                                    Wm1, bm1, Wm2, bm2, Wu, We, be,
                                    Wupd, Wcomb, c0, Wec, ball, W2f);
  k_scan<<<1, 1024, 0, stream>>>(deg, rowptr);
  k_scatter<<<NE/256, 256, 0, stream>>>(from, toi, rowptr, cursor, fromArr, eidxArr);
  k_tgemm<<<NE/128, 256, 0, stream>>>(ef, eidxArr, Wec, Tp);

  const float* hc = h0;
  float* hn = h1;
  const unsigned short* hcb = hb0;
  unsigned short* hnb = hb1;
  for (int s = 0; s < 3; ++s) {
    k_agemm<<<NN/64, 256, 0, stream>>>(hcb, W2f, ball, Afb, Atbb);
    k_aggregate<<<NN/8, 128, 0, stream>>>(Afb, Atbb, rowptr, fromArr, Tp, u);
    k_update<<<512, 256, 0, stream>>>(hc, u, deg, Wupd, Wcomb, c0, bu, hn, hnb);
    float* t = (float*)hc; hc = hn; hn = t;
    unsigned short* tb = (unsigned short*)hcb; hcb = hnb; hnb = tb;
  }
  k_gate<<<512, 256, 0, stream>>>(hc, Wa, ba, gv);
  k_hinge<<<512, 64, 0, stream>>>(gv, Wg, out);
}

// Round 10
// 407.068 us; speedup vs baseline: 1.1395x; 1.0282x over previous
//
#include <hip/hip_runtime.h>

static constexpr int NN = 32768;   // nodes
static constexpr int NE = 262144;  // edges
static constexpr int NG = 1024;    // graphs

typedef __attribute__((ext_vector_type(8))) short short8v;
typedef __attribute__((ext_vector_type(4))) float f32x4;
union Frag { short8v v; short4 p[2]; };

__device__ __forceinline__ float4 ld4(const float* p){ return *reinterpret_cast<const float4*>(p); }
__device__ __forceinline__ void st4(float* p, const float4 v){ *reinterpret_cast<float4*>(p) = v; }
__device__ __forceinline__ void fma4(float4& a, const float s, const float4 w){
  a.x = fmaf(s, w.x, a.x); a.y = fmaf(s, w.y, a.y); a.z = fmaf(s, w.z, a.z); a.w = fmaf(s, w.w, a.w);
}
__device__ __forceinline__ unsigned short f2bf(float f){
  unsigned x = __float_as_uint(f);
  return (unsigned short)((x + 0x7FFFu + ((x >> 16) & 1u)) >> 16);  // RNE
}
__device__ __forceinline__ float bf2f(unsigned short u){
  return __uint_as_float((unsigned)u << 16);
}

// ---------- fused setup: node_enc (blocks 0..8191) | hist (8192..9215) | precomp (9216..9344) ----------
// precomp: Wupd | Wcomb | c0 | ball | Wec2f (MFMA B-frag of We@Wm1_e, K padded 16->32 w/ zeros)
//          | W2f (MFMA B-frag of Wm1 node-part, K=64, 16 col-tiles)
__global__ __launch_bounds__(256) void k_setup(const float* __restrict__ nf, const float* __restrict__ Wn,
                                               const float* __restrict__ bn, float* __restrict__ h,
                                               unsigned short* __restrict__ hb,
                                               const int* __restrict__ toi, int* __restrict__ deg,
                                               const float* __restrict__ Wm1, const float* __restrict__ bm1,
                                               const float* __restrict__ Wm2, const float* __restrict__ bm2,
                                               const float* __restrict__ Wu,
                                               const float* __restrict__ We, const float* __restrict__ be,
                                               float* __restrict__ Wupd, float* __restrict__ Wcomb,
                                               float* __restrict__ c0, float* __restrict__ ball,
                                               unsigned short* __restrict__ Wec2f,
                                               unsigned short* __restrict__ W2f) {
  int b = blockIdx.x;
  int tid = threadIdx.x;
  if (b < 8192) {
    __shared__ __align__(16) float Wn_s[32*64];
    for (int i = tid; i < 32*64; i += 256) Wn_s[i] = Wn[i];
    __syncthreads();
    int j = tid & 63, nl = tid >> 6;
    int n = b*4 + nl;
    const float* r = nf + n*32;
    float acc = bn[j];
    #pragma unroll
    for (int k = 0; k < 32; ++k) acc = fmaf(r[k], Wn_s[k*64+j], acc);
    h[n*64+j] = acc;
    hb[n*64+j] = f2bf(acc);
  } else if (b < 8192 + 1024) {
    int e = (b - 8192)*256 + tid;
    atomicAdd(&deg[toi[e]], 1);
  } else {
    int idx = (b - 9216)*256 + tid;
    if (idx < 4096) {
      int k = idx >> 6, j = idx & 63;
      Wupd[idx] = Wu[k*64 + j] + ((k == j) ? 1.f : 0.f);
    } else if (idx < 12288) {
      int i2 = idx - 4096;
      int k = i2 >> 6, j = i2 & 63;
      float s = 0.f;
      for (int i = 0; i < 128; ++i) s = fmaf(Wm2[k*128 + i], Wu[(64+i)*64 + j], s);
      Wcomb[i2] = s;
    } else if (idx < 12352) {
      int j = idx - 12288;
      float s = 0.f;
      for (int i = 0; i < 128; ++i) s = fmaf(bm2[i], Wu[(64+i)*64 + j], s);
      c0[j] = s;
    } else if (idx < 12480) {
      int j = idx - 12352;
      float s = bm1[j];
      for (int i = 0; i < 16; ++i) s = fmaf(be[i], Wm1[(128+i)*128 + j], s);
      ball[j] = s;
    } else if (idx < 12480 + 4096) {
      // Wec2f: B-frag order, tile ct<8, K=32 (k>=16 zero).
      int t = idx - 12480;
      int ct = t >> 9;
      int r2 = t & 511;
      int lane = r2 >> 3;
      int i = r2 & 7;
      int k = ((lane>>4)<<2) + (i&3) + ((i>>2)<<4);
      int col = ct*16 + (lane & 15);
      float val = 0.f;
      if (k < 16) {
        for (int q = 0; q < 16; ++q) val = fmaf(We[k*16 + q], Wm1[(128+q)*128 + col], val);
      }
      Wec2f[t] = f2bf(val);
    } else if (idx < 16576 + 16384) {
      int t = idx - 16576;
      int ks = t >> 13;
      int r = t & 8191;
      int ct = r >> 9;
      int r2 = r & 511;
      int lane = r2 >> 3;
      int i = r2 & 7;
      int k = ks*32 + ((i>>2)<<4) + ((lane>>4)<<2) + (i&3);
      int col = ct*16 + (lane & 15);
      float val = (col < 128) ? Wm1[k*128 + col] : Wm1[(64+k)*128 + (col-128)];
      W2f[t] = f2bf(val);
    }
  }
}

// ---------- exclusive scan of deg[32768] -> rowptr[32769] ----------
__global__ __launch_bounds__(1024) void k_scan(const int* __restrict__ deg, int* __restrict__ rowptr) {
  __shared__ int sums[1024];
  int t = threadIdx.x;
  int base = t * 32;
  int local[32];
  int s = 0;
  #pragma unroll
  for (int i = 0; i < 32; ++i) { local[i] = s; s += deg[base + i]; }
  sums[t] = s;
  __syncthreads();
  for (int off = 1; off < 1024; off <<= 1) {
    int tmp = (t >= off) ? sums[t - off] : 0;
    __syncthreads();
    sums[t] += tmp;
    __syncthreads();
  }
  int boff = sums[t] - s;
  #pragma unroll
  for (int i = 0; i < 32; ++i) rowptr[base + i] = boff + local[i];
  if (t == 1023) rowptr[NN] = sums[1023];
}

// ---------- scatter edges into SoA CSR: fromArr[slot]; efb[slot] = bf16(ef[e]) ----------
__global__ __launch_bounds__(256) void k_scatter(const int* __restrict__ from, const int* __restrict__ toi,
                                                 const int* __restrict__ rowptr, int* __restrict__ cursor,
                                                 const float* __restrict__ ef,
                                                 int* __restrict__ fromArr, unsigned short* __restrict__ efb) {
  int e = blockIdx.x*256 + threadIdx.x;
  int v = toi[e];
  int pos = atomicAdd(&cursor[v], 1);
  int slot = rowptr[v] + pos;
  fromArr[slot] = from[e];
  const float* er = ef + (size_t)e*16;
  unsigned short tmp[16];
  #pragma unroll
  for (int k = 0; k < 16; ++k) tmp[k] = f2bf(er[k]);
  #pragma unroll
  for (int q = 0; q < 4; ++q)
    *reinterpret_cast<ushort4*>(efb + (size_t)slot*16 + q*4) =
        make_ushort4(tmp[q*4], tmp[q*4+1], tmp[q*4+2], tmp[q*4+3]);
}

// ---------- MFMA tgemm: Tp(NE x 128, bf16) = efb @ Wec (K=16 padded to 32), CSR order ----------
// No LDS. Per wave: 4 tiles of 16 edges; 8 col-tile MFMAs each. B-frags hoisted in regs.
__global__ __launch_bounds__(256) void k_tgemm(const unsigned short* __restrict__ efb,
                                               const unsigned short* __restrict__ Wec2f,
                                               unsigned short* __restrict__ Tp) {
  int tid = threadIdx.x;
  int wv = tid >> 6, lane = tid & 63;
  int r = lane & 15, kg = lane >> 4;
  Frag b[8];
  #pragma unroll
  for (int ct = 0; ct < 8; ++ct)
    b[ct].v = *reinterpret_cast<const short8v*>(Wec2f + ((size_t)(ct*64 + lane) << 3));
  size_t ebase = (size_t)blockIdx.x * 256 + wv * 64;
  #pragma unroll
  for (int t = 0; t < 4; ++t) {
    size_t e0 = ebase + t*16;
    Frag a;
    a.p[0] = *reinterpret_cast<const short4*>(efb + (e0 + r)*16 + kg*4);
    a.p[1] = make_short4(0, 0, 0, 0);
    #pragma unroll
    for (int ct = 0; ct < 8; ++ct) {
      f32x4 acc = {0.f, 0.f, 0.f, 0.f};
      acc = __builtin_amdgcn_mfma_f32_16x16x32_bf16(a.v, b[ct].v, acc, 0, 0, 0);
      #pragma unroll
      for (int i = 0; i < 4; ++i)
        Tp[(e0 + kg*4 + i)*128 + ct*16 + r] = f2bf(acc[i]);
    }
  }
}

// ---------- MFMA agemm: Afb/Atbb (bf16) = hb @ W2f (+ball) ----------
__global__ __launch_bounds__(256) void k_agemm(const unsigned short* __restrict__ hb,
                                               const unsigned short* __restrict__ W2f,
                                               const float* __restrict__ ball,
                                               unsigned short* __restrict__ Afb,
                                               unsigned short* __restrict__ Atbb) {
  int tid = threadIdx.x;
  int wv = tid >> 6, lane = tid & 63;
  int n0 = blockIdx.x*64 + wv*16;
  int r = lane & 15, kg = lane >> 4;
  const unsigned short* hrow = hb + (size_t)(n0 + r)*64;
  Frag a0, a1;
  a0.p[0] = *reinterpret_cast<const short4*>(hrow + kg*4);
  a0.p[1] = *reinterpret_cast<const short4*>(hrow + 16 + kg*4);
  a1.p[0] = *reinterpret_cast<const short4*>(hrow + 32 + kg*4);
  a1.p[1] = *reinterpret_cast<const short4*>(hrow + 48 + kg*4);
  #pragma unroll
  for (int ct = 0; ct < 16; ++ct) {
    Frag b0, b1;
    b0.v = *reinterpret_cast<const short8v*>(W2f + ((size_t)(ct*64 + lane) << 3));
    b1.v = *reinterpret_cast<const short8v*>(W2f + ((size_t)((16+ct)*64 + lane) << 3));
    f32x4 acc = {0.f, 0.f, 0.f, 0.f};
    acc = __builtin_amdgcn_mfma_f32_16x16x32_bf16(a0.v, b0.v, acc, 0, 0, 0);
    acc = __builtin_amdgcn_mfma_f32_16x16x32_bf16(a1.v, b1.v, acc, 0, 0, 0);
    int cj = ct*16 + r;
    int nb = n0 + kg*4;
    if (cj < 128) {
      #pragma unroll
      for (int i = 0; i < 4; ++i)
        Afb[(size_t)(nb+i)*128 + cj] = f2bf(acc[i]);
    } else {
      float bb = ball[cj-128];
      #pragma unroll
      for (int i = 0; i < 4; ++i)
        Atbb[(size_t)(nb+i)*128 + (cj-128)] = f2bf(acc[i] + bb);
    }
  }
}

// ---------- u[v] = sum_{s in row v} relu(Afb[from[s]] + Atbb[v] + Tp[s]) ----------
__global__ __launch_bounds__(128) void k_aggregate(const unsigned short* __restrict__ Afb,
                                                   const unsigned short* __restrict__ Atbb,
                                                   const int* __restrict__ rowptr,
                                                   const int* __restrict__ fromArr,
                                                   const unsigned short* __restrict__ Tp,
                                                   float* __restrict__ u) {
  int j = threadIdx.x;  // 0..127
  int v0 = blockIdx.x * 8;
  for (int v = v0; v < v0 + 8; ++v) {
    float atv = bf2f(Atbb[(size_t)v*128 + j]);
    int s0 = rowptr[v], s1 = rowptr[v+1];
    float acc = 0.f;
    int s = s0;
    for (; s + 8 <= s1; s += 8) {
      int f0 = fromArr[s],   f1 = fromArr[s+1], f2 = fromArr[s+2], f3 = fromArr[s+3];
      int f4 = fromArr[s+4], f5 = fromArr[s+5], f6 = fromArr[s+6], f7 = fromArr[s+7];
      float a0 = bf2f(Afb[(size_t)f0*128 + j]);
      float a1 = bf2f(Afb[(size_t)f1*128 + j]);
      float a2 = bf2f(Afb[(size_t)f2*128 + j]);
      float a3 = bf2f(Afb[(size_t)f3*128 + j]);
      float a4 = bf2f(Afb[(size_t)f4*128 + j]);
      float a5 = bf2f(Afb[(size_t)f5*128 + j]);
      float a6 = bf2f(Afb[(size_t)f6*128 + j]);
      float a7 = bf2f(Afb[(size_t)f7*128 + j]);
      float t0 = bf2f(Tp[(size_t)(s  )*128 + j]);
      float t1 = bf2f(Tp[(size_t)(s+1)*128 + j]);
      float t2 = bf2f(Tp[(size_t)(s+2)*128 + j]);
      float t3 = bf2f(Tp[(size_t)(s+3)*128 + j]);
      float t4 = bf2f(Tp[(size_t)(s+4)*128 + j]);
      float t5 = bf2f(Tp[(size_t)(s+5)*128 + j]);
      float t6 = bf2f(Tp[(size_t)(s+6)*128 + j]);
      float t7 = bf2f(Tp[(size_t)(s+7)*128 + j]);
      acc += fmaxf(a0 + atv + t0, 0.f) + fmaxf(a1 + atv + t1, 0.f)
           + fmaxf(a2 + atv + t2, 0.f) + fmaxf(a3 + atv + t3, 0.f)
           + fmaxf(a4 + atv + t4, 0.f) + fmaxf(a5 + atv + t5, 0.f)
           + fmaxf(a6 + atv + t6, 0.f) + fmaxf(a7 + atv + t7, 0.f);
    }
    for (; s < s1; ++s) {
      int f = fromArr[s];
      float a = bf2f(Afb[(size_t)f*128 + j]);
      float t = bf2f(Tp[(size_t)s*128 + j]);
      acc += fmaxf(a + atv + t, 0.f);
    }
    u[(size_t)v*128 + j] = acc;
  }
}

// ---------- h_out = h@Wupd + u@Wcomb + deg*c0 + bu  (fp32, persistent; also emits bf16 h) ----------
__global__ __launch_bounds__(256) void k_update(const float* __restrict__ h, const float* __restrict__ u,
                                                const int* __restrict__ deg,
                                                const float* __restrict__ Wupd, const float* __restrict__ Wcomb,
                                                const float* __restrict__ c0, const float* __restrict__ bu,
                                                float* __restrict__ hout, unsigned short* __restrict__ hbout) {
  __shared__ __align__(16) float Wall_s[192*64];
  __shared__ __align__(16) float h_s[32*64];
  __shared__ __align__(16) float u_s[32*128];
  int tid = threadIdx.x;
  for (int idx = tid; idx < 4096; idx += 256) Wall_s[idx] = Wupd[idx];
  for (int idx = tid; idx < 8192; idx += 256) Wall_s[4096 + idx] = Wcomb[idx];
  int cg = tid & 15;
  int nl = tid >> 4;
  float4 c04 = ld4(c0 + 4*cg);
  float4 bu4 = ld4(bu + 4*cg);
  for (int tile = blockIdx.x; tile < 1024; tile += gridDim.x) {
    int base = tile * 32;
    __syncthreads();
    for (int idx = tid; idx < 2048; idx += 256) h_s[idx] = h[base*64 + idx];
    for (int idx = tid; idx < 4096; idx += 256) u_s[idx] = u[base*128 + idx];
    __syncthreads();
    float4 acc[2];
    acc[0] = make_float4(0,0,0,0); acc[1] = make_float4(0,0,0,0);
    for (int k4 = 0; k4 < 16; ++k4) {
      float4 w[4];
      #pragma unroll
      for (int q = 0; q < 4; ++q) w[q] = ld4(&Wall_s[(k4*4+q)*64 + 4*cg]);
      #pragma unroll
      for (int i = 0; i < 2; ++i) {
        float4 h4 = ld4(&h_s[(nl + 16*i)*64 + k4*4]);
        fma4(acc[i], h4.x, w[0]); fma4(acc[i], h4.y, w[1]);
        fma4(acc[i], h4.z, w[2]); fma4(acc[i], h4.w, w[3]);
      }
    }
    for (int k4 = 0; k4 < 32; ++k4) {
      float4 w[4];
      #pragma unroll
      for (int q = 0; q < 4; ++q) w[q] = ld4(&Wall_s[(64 + k4*4+q)*64 + 4*cg]);
      #pragma unroll
      for (int i = 0; i < 2; ++i) {
        float4 u4 = ld4(&u_s[(nl + 16*i)*128 + k4*4]);
        fma4(acc[i], u4.x, w[0]); fma4(acc[i], u4.y, w[1]);
        fma4(acc[i], u4.z, w[2]); fma4(acc[i], u4.w, w[3]);
      }
    }
    #pragma unroll
    for (int i = 0; i < 2; ++i) {
      int n = base + nl + 16*i;
      float dg = (float)deg[n];
      float4 r = acc[i];
      r.x += dg*c04.x + bu4.x; r.y += dg*c04.y + bu4.y;
      r.z += dg*c04.z + bu4.z; r.w += dg*c04.w + bu4.w;
      st4(&hout[(size_t)n*64 + 4*cg], r);
      ushort4 rb;
      rb.x = f2bf(r.x); rb.y = f2bf(r.y); rb.z = f2bf(r.z); rb.w = f2bf(r.w);
      *reinterpret_cast<ushort4*>(hbout + (size_t)n*64 + 4*cg) = rb;
    }
  }
}

// ---------- per-graph gate+pool (persistent) ----------
__global__ __launch_bounds__(256) void k_gate(const float* __restrict__ h,
                                              const float* __restrict__ Wa, const float* __restrict__ ba,
                                              float* __restrict__ gv) {
  __shared__ __align__(16) float Wa_s[64*256];
  __shared__ __align__(16) float h_s[32*64];
  __shared__ __align__(16) float4 part_s[8][32];
  int tid = threadIdx.x;
  for (int idx = tid; idx < 64*256; idx += 256) Wa_s[idx] = Wa[idx];
  int cg = tid & 31;
  int nl = tid >> 5;
  float4 ba4a = ld4(ba + 4*cg);
  float4 ba4b = ld4(ba + 128 + 4*cg);
  for (int g = blockIdx.x; g < NG; g += gridDim.x) {
    __syncthreads();
    for (int idx = tid; idx < 2048; idx += 256) h_s[idx] = h[(size_t)g*2048 + idx];
    __syncthreads();
    float4 aA[4], aB[4];
    #pragma unroll
    for (int i = 0; i < 4; ++i) { aA[i] = make_float4(0,0,0,0); aB[i] = make_float4(0,0,0,0); }
    for (int k4 = 0; k4 < 16; ++k4) {
      float4 wa[4], wb[4];
      #pragma unroll
      for (int q = 0; q < 4; ++q) {
        wa[q] = ld4(&Wa_s[(k4*4+q)*256 + 4*cg]);
        wb[q] = ld4(&Wa_s[(k4*4+q)*256 + 128 + 4*cg]);
      }
      #pragma unroll
      for (int i = 0; i < 4; ++i) {
        float4 h4 = ld4(&h_s[(nl + 8*i)*64 + k4*4]);
        fma4(aA[i], h4.x, wa[0]); fma4(aA[i], h4.y, wa[1]); fma4(aA[i], h4.z, wa[2]); fma4(aA[i], h4.w, wa[3]);
        fma4(aB[i], h4.x, wb[0]); fma4(aB[i], h4.y, wb[1]); fma4(aB[i], h4.z, wb[2]); fma4(aB[i], h4.w, wb[3]);
      }
    }
    float4 sum = make_float4(0,0,0,0);
    #pragma unroll
    for (int i = 0; i < 4; ++i) {
      float ax = aA[i].x + ba4a.x, ay = aA[i].y + ba4a.y, az = aA[i].z + ba4a.z, aw = aA[i].w + ba4a.w;
      float bx = aB[i].x + ba4b.x, by = aB[i].y + ba4b.y, bz = aB[i].z + ba4b.z, bw = aB[i].w + ba4b.w;
      sum.x += bx / (1.f + __expf(-ax));
      sum.y += by / (1.f + __expf(-ay));
      sum.z += bz / (1.f + __expf(-az));
      sum.w += bw / (1.f + __expf(-aw));
    }
    part_s[nl][cg] = sum;
    __syncthreads();
    if (tid < 32) {
      float4 s = part_s[0][tid];
      #pragma unroll
      for (int n = 1; n < 8; ++n) {
        float4 p = part_s[n][tid];
        s.x += p.x; s.y += p.y; s.z += p.z; s.w += p.w;
      }
      st4(&gv[(size_t)g*128 + tid*4], s);
    }
  }
}

// ---------- pairs: out[p] = -sum relu((gv[2p]-gv[2p+1]) @ Wg) ----------
__global__ __launch_bounds__(64) void k_hinge(const float* __restrict__ gv,
                                              const float* __restrict__ Wg,
                                              float* __restrict__ out) {
  __shared__ float d_s[128];
  int p = blockIdx.x, tid = threadIdx.x;
  d_s[tid]      = gv[(2*p)*128 + tid]      - gv[(2*p+1)*128 + tid];
  d_s[tid + 64] = gv[(2*p)*128 + 64 + tid] - gv[(2*p+1)*128 + 64 + tid];
  __syncthreads();
  float a0 = 0.f, a1 = 0.f;
  for (int k = 0; k < 128; ++k) {
    float d = d_s[k];
    a0 = fmaf(d, Wg[k*128 + tid], a0);
    a1 = fmaf(d, Wg[k*128 + 64 + tid], a1);
  }
  float r = fmaxf(a0, 0.f) + fmaxf(a1, 0.f);
  #pragma unroll
  for (int off = 32; off > 0; off >>= 1) r += __shfl_down(r, off, 64);
  if (tid == 0) out[p] = -r;
}

extern "C" void kernel_launch(void* const* d_in, const int* in_sizes, int n_in,
                              void* d_out, int out_size, void* d_ws, size_t ws_size,
                              hipStream_t stream) {
  const float* nf  = (const float*)d_in[0];
  const float* ef  = (const float*)d_in[1];
  const int*   from= (const int*)d_in[2];
  const int*   toi = (const int*)d_in[3];
  const float* Wn  = (const float*)d_in[5];
  const float* bn  = (const float*)d_in[6];
  const float* We  = (const float*)d_in[7];
  const float* be  = (const float*)d_in[8];
  const float* Wm1 = (const float*)d_in[9];
  const float* bm1 = (const float*)d_in[10];
  const float* Wm2 = (const float*)d_in[11];
  const float* bm2 = (const float*)d_in[12];
  const float* Wu  = (const float*)d_in[13];
  const float* bu  = (const float*)d_in[14];
  const float* Wa  = (const float*)d_in[15];
  const float* ba  = (const float*)d_in[16];
  const float* Wg  = (const float*)d_in[17];
  float* out = (float*)d_out;

  float* fb    = (float*)d_ws;
  float* h0    = fb;                    // 2,097,152 floats
  float* h1    = h0 + 2097152;          // 2,097,152
  float* u     = h1 + 2097152;          // 4,194,304
  float* gv    = u + 4194304;           // 131,072
  float* Wupd  = gv + 131072;           // 4,096
  float* Wcomb = Wupd + 4096;           // 8,192
  float* c0    = Wcomb + 8192;          // 64
  float* ball  = c0 + 64;               // 128
  unsigned short* hb0   = (unsigned short*)(ball + 128);  // NN*64
  unsigned short* hb1   = hb0 + (size_t)NN*64;            // NN*64
  unsigned short* Afb   = hb1 + (size_t)NN*64;            // NN*128
  unsigned short* Atbb  = Afb + (size_t)NN*128;           // NN*128
  unsigned short* W2f   = Atbb + (size_t)NN*128;          // 16384
  unsigned short* Wec2f = W2f + 16384;                    // 4096
  unsigned short* Tp    = Wec2f + 4096;                   // NE*128
  unsigned short* efb   = Tp + (size_t)NE*128;            // NE*16
  int*   fromArr = (int*)(efb + (size_t)NE*16);           // NE
  int*   deg   = fromArr + NE;          // NN
  int*   rowptr= deg + NN;              // NN+1
  int*   cursor= rowptr + NN + 1;       // NN

  // Zero-init the ENTIRE used workspace region every call: the harness
  // re-poisons d_ws to 0xAA before each timed launch, while the first
  // correctness call sees fresh (zero) pages. Forcing identical initial
  // state removes any poison-sensitivity (round-8 post-timing divergence).
  size_t used_bytes = (size_t)((char*)(cursor + NN) - (char*)d_ws);
  hipMemsetAsync(d_ws, 0, used_bytes, stream);

  k_setup<<<9345, 256, 0, stream>>>(nf, Wn, bn, h0, hb0, toi, deg,
                                    Wm1, bm1, Wm2, bm2, Wu, We, be,
                                    Wupd, Wcomb, c0, ball, Wec2f, W2f);
  k_scan<<<1, 1024, 0, stream>>>(deg, rowptr);
  k_scatter<<<NE/256, 256, 0, stream>>>(from, toi, rowptr, cursor, ef, fromArr, efb);
  k_tgemm<<<NE/256, 256, 0, stream>>>(efb, Wec2f, Tp);

  const float* hc = h0;
  float* hn = h1;
  const unsigned short* hcb = hb0;
  unsigned short* hnb = hb1;
  for (int s = 0; s < 3; ++s) {
    k_agemm<<<NN/64, 256, 0, stream>>>(hcb, W2f, ball, Afb, Atbb);
    k_aggregate<<<NN/8, 128, 0, stream>>>(Afb, Atbb, rowptr, fromArr, Tp, u);
    k_update<<<512, 256, 0, stream>>>(hc, u, deg, Wupd, Wcomb, c0, bu, hn, hnb);
    float* t = (float*)hc; hc = hn; hn = t;
    unsigned short* tb = (unsigned short*)hcb; hcb = hnb; hnb = tb;
  }
  k_gate<<<512, 256, 0, stream>>>(hc, Wa, ba, gv);
  k_hinge<<<512, 64, 0, stream>>>(gv, Wg, out);
}